// Round 2
// baseline (13000.041 us; speedup 1.0000x reference)
//
#include <hip/hip_runtime.h>
#include <hip/hip_fp16.h>

// RNN_14078902797083: 2-layer tanh RNN + FC + softmax, fp32 in/out.
// B=64, T=2048, IN=256, H=512, NCLASS=2.
//
// R6: fix the scan's register spill. R5's scan declared unsigned w[192] but
// compiled to VGPR_Count=128 -> the W_hh slice spilled (AGPR/scratch) and was
// re-read every step (~1400 extra VALU cyc/step; 3.35 ms/scan vs ~0.9 ms
// floor). Now: w as uint4 w4[48] with fully-unrolled static indexing (SROA),
// amdgpu_waves_per_eu(2,2) so the allocator budgets 256 VGPRs for the
// mandatory 2-waves/SIMD layout, fast tanh (exp+rcp, ~2e-6 abs err) on the
// serial path, and 2-deep xw prefetch. GEMM/transpose/FC unchanged from R5.

#define BB 64
#define TT 2048
#define IN 256
#define HH 512
#define MM (BB * TT)          // 131072 rows

// workspace layout (bytes)
#define BUF0_OFF 0ull                      // [B][T][H] f32 = 256 MB (xw0 -> h1 -> xw1, in place)
#define WT_OFF   268435456ull              // W^T scratch, 1 MB (WT0 then WT1, disjoint lifetimes)
#define H2L_OFF  269484032ull              // [B][H] f32 last hidden = 128 KB

// ---- recurrent weight split ----
#define KREG 384                 // k-range held in VGPRs (48 uint4 = 192 VGPRs)
#define KLDS (HH - KREG)         // 128 -> LDS as uint4 [KLDS/8][HH] = 128 KB
#define NCH_REG (KREG / 8)       // 48 uint4 h-chunks from regs
#define NCH_LDS (KLDS / 8)       // 16 uint4 h-chunks from LDS
#define SCAN_SMEM (NCH_LDS * HH * 16 + 2 * 256 * 4)   // 131072 + 2048 = 133120 B

typedef _Float16 v2h __attribute__((ext_vector_type(2)));

__device__ __forceinline__ float fdot2u(unsigned a, unsigned b, float c) {
#if __has_builtin(__builtin_amdgcn_fdot2)
    union { unsigned u; v2h h; } ua, ub;
    ua.u = a; ub.u = b;
    return __builtin_amdgcn_fdot2(ua.h, ub.h, c, false);
#else
    __half2 ah = *reinterpret_cast<__half2*>(&a);
    __half2 bh = *reinterpret_cast<__half2*>(&b);
    float2 fa = __half22float2(ah), fb = __half22float2(bh);
    return fmaf(fa.y, fb.y, fmaf(fa.x, fb.x, c));
#endif
}

__device__ __forceinline__ unsigned pk2(float x, float y) {
    unsigned lo = (unsigned)__half_as_ushort(__float2half(x));
    unsigned hi = (unsigned)__half_as_ushort(__float2half(y));
    return lo | (hi << 16);
}

// fast tanh: copysign((1-e)/(1+e), x) with e = exp(-2|x|). No overflow for any x.
// v_exp relerr ~1e-6, v_rcp ~1e-6 -> abs err ~2e-6, far below the fp16-W noise.
__device__ __forceinline__ float fast_tanh(float x) {
    const float ax = __builtin_fabsf(x);
    const float e  = __expf(-2.f * ax);
    const float r  = (1.f - e) * __builtin_amdgcn_rcpf(1.f + e);
    return __builtin_copysignf(r, x);
}

// -------------------- W transpose: W[512][K] -> WT[K][512] --------------------
__global__ void transpose_w(const float* __restrict__ W, float* __restrict__ WT, int K)
{
    __shared__ float tile[32][33];
    const int k0 = blockIdx.x * 32;
    const int c0 = blockIdx.y * 32;
    const int tx = threadIdx.x & 31;
    const int ty = threadIdx.x >> 5;          // 0..7
    #pragma unroll
    for (int i = ty; i < 32; i += 8)
        tile[i][tx] = W[(size_t)(c0 + i) * K + k0 + tx];   // coalesced along k
    __syncthreads();
    #pragma unroll
    for (int i = ty; i < 32; i += 8)
        WT[(size_t)(k0 + i) * HH + c0 + tx] = tile[tx][i]; // coalesced along c
}

// -------------------- input projection GEMM: out = A @ W^T + (b1+b2) ----------
// A [M][K] (may alias out), WT [K][512], out [M][512]. 32 rows/WG, full N.
// Full-K A staging in LDS BEFORE any write -> in-place safe per 32-row block.
template <int K>
__global__ __launch_bounds__(256, 2)
void gemm_xw(const float* A, const float* __restrict__ WT,
             const float* __restrict__ b1, const float* __restrict__ b2,
             float* out)
{
    extern __shared__ char smem[];
    float* As = (float*)smem;                 // [32][K]
    const int m0 = blockIdx.x * 32;
    const int tid = threadIdx.x;

    const float* Ab = A + (size_t)m0 * K;
    #pragma unroll
    for (int i = 0; i < (32 * K) / 1024; ++i) {
        const int idx = tid * 4 + i * 1024;
        *(float4*)&As[idx] = *(const float4*)&Ab[idx];
    }
    __syncthreads();

    const int tc = tid & 63;                  // col base lane; cols c = tc + 64*cc
    const int r0 = (tid >> 6) * 8;            // 8 rows per thread

    float acc[8][8];
    #pragma unroll
    for (int cc = 0; cc < 8; ++cc) {
        const int c = tc + 64 * cc;
        const float bb = b1[c] + b2[c];
        #pragma unroll
        for (int rr = 0; rr < 8; ++rr) acc[rr][cc] = bb;
    }

    #pragma unroll 2
    for (int k = 0; k < K; k += 4) {
        float4 av4[8];
        #pragma unroll
        for (int rr = 0; rr < 8; ++rr)
            av4[rr] = *(const float4*)&As[(r0 + rr) * K + k];   // wave-uniform: broadcast
        #pragma unroll
        for (int kk = 0; kk < 4; ++kk) {
            float wv[8];
            #pragma unroll
            for (int cc = 0; cc < 8; ++cc)
                wv[cc] = WT[(size_t)(k + kk) * HH + tc + 64 * cc];  // lane-consecutive: coalesced
            #pragma unroll
            for (int rr = 0; rr < 8; ++rr) {
                const float a = ((const float*)&av4[rr])[kk];
                #pragma unroll
                for (int cc = 0; cc < 8; ++cc)
                    acc[rr][cc] = fmaf(a, wv[cc], acc[rr][cc]);
            }
        }
    }

    #pragma unroll
    for (int rr = 0; rr < 8; ++rr) {
        float* orow = out + (size_t)(m0 + r0 + rr) * HH;
        #pragma unroll
        for (int cc = 0; cc < 8; ++cc)
            orow[tc + 64 * cc] = acc[rr][cc];
    }
}

// -------------------- recurrent scan: one WG per batch, no inter-WG comm ------
template <bool WRITE_SEQ>
__global__ __launch_bounds__(512)
__attribute__((amdgpu_waves_per_eu(2, 2)))
void scan_rnn(const float* xw,                 // [B][T][H]; aliased by hseq when WRITE_SEQ
              const float* __restrict__ Whh,   // [H][H]
              float* hseq)                     // WRITE_SEQ: [B][T][H] (alias of xw); else [B][H]
{
    extern __shared__ char smem[];
    uint4* wlds4   = (uint4*)smem;                              // [NCH_LDS][HH]
    unsigned* hpk  = (unsigned*)(smem + NCH_LDS * HH * 16);     // [2][256] packed fp16 h

    const int b = blockIdx.x;
    const int j = threadIdx.x;                 // output row 0..511

    // ---- one-time: W_hh row j, k=0..383 as 48 uint4 of packed fp16 (SROA'd) ----
    const float* wrow = Whh + (size_t)j * HH;
    uint4 w4[NCH_REG];
    #pragma unroll
    for (int c = 0; c < NCH_REG; ++c) {
        const float* p = wrow + c * 8;
        const float4 f0 = *(const float4*)(p);
        const float4 f1 = *(const float4*)(p + 4);
        w4[c].x = pk2(f0.x, f0.y);
        w4[c].y = pk2(f0.z, f0.w);
        w4[c].z = pk2(f1.x, f1.y);
        w4[c].w = pk2(f1.z, f1.w);
    }
    // ---- k=384..511 -> LDS [NCH_LDS][HH] uint4, lane-consecutive ----
    #pragma unroll
    for (int qq = 0; qq < NCH_LDS; ++qq) {
        const float* p = wrow + KREG + qq * 8;
        const float4 f0 = *(const float4*)(p);
        const float4 f1 = *(const float4*)(p + 4);
        uint4 v;
        v.x = pk2(f0.x, f0.y); v.y = pk2(f0.z, f0.w);
        v.z = pk2(f1.x, f1.y); v.w = pk2(f1.z, f1.w);
        wlds4[qq * HH + j] = v;
    }
    __syncthreads();

    const float* xrow = xw + (size_t)b * TT * HH + j;
    float* srow = WRITE_SEQ ? (hseq + (size_t)b * TT * HH + j) : nullptr;
    unsigned short* hw0 = (unsigned short*)hpk;          // parity-0 publish buffer
    unsigned short* hw1 = (unsigned short*)(hpk + 256);  // parity-1 publish buffer

    float xw_cur = xrow[0];
    float xw_n1  = xrow[HH];
    for (int t = 0; t < TT; ++t) {
        const int t2 = (t + 2 < TT) ? (t + 2) : (TT - 1);
        const float xw_n2 = xrow[(size_t)t2 * HH];       // 2-deep prefetch

        float z = xw_cur;
        if (t > 0) {
            // read parity (t-1)&1 = (t&1)^1
            const unsigned* hp = (t & 1) ? (const unsigned*)hpk : (const unsigned*)(hpk + 256);
            float a0 = 0.f, a1 = 0.f, a2 = 0.f, a3 = 0.f;
            #pragma unroll
            for (int c = 0; c < NCH_REG; ++c) {
                const uint4 hv = *(const uint4*)(hp + c * 4);   // uniform addr: LDS broadcast
                a0 = fdot2u(w4[c].x, hv.x, a0);
                a1 = fdot2u(w4[c].y, hv.y, a1);
                a2 = fdot2u(w4[c].z, hv.z, a2);
                a3 = fdot2u(w4[c].w, hv.w, a3);
            }
            #pragma unroll
            for (int qq = 0; qq < NCH_LDS; ++qq) {
                const uint4 wv = wlds4[qq * HH + j];            // lane-consecutive: conflict-free
                const uint4 hv = *(const uint4*)(hp + NCH_REG * 4 + qq * 4);
                a0 = fdot2u(wv.x, hv.x, a0);
                a1 = fdot2u(wv.y, hv.y, a1);
                a2 = fdot2u(wv.z, hv.z, a2);
                a3 = fdot2u(wv.w, hv.w, a3);
            }
            z += (a0 + a1) + (a2 + a3);
        }
        const float h = fast_tanh(z);

        // publish h for next step (write parity t&1 != read parity -> 1 barrier/step)
        ((t & 1) ? hw1 : hw0)[j] = __half_as_ushort(__float2half(h));

        if (WRITE_SEQ) {
            srow[(size_t)t * HH] = h;          // in-place over xw[b][t][j]: thread-local element
        } else if (t == TT - 1) {
            hseq[b * HH + j] = h;
        }
        xw_cur = xw_n1;
        xw_n1  = xw_n2;
        __syncthreads();
    }
}

// -------------------- FC + softmax --------------------
__global__ void fc_kernel(const float* __restrict__ h2, const float* __restrict__ w,
                          const float* __restrict__ bvec, float* __restrict__ out)
{
    const int b = threadIdx.x;   // 64 threads
    float z0 = bvec[0], z1 = bvec[1];
    #pragma unroll 4
    for (int k = 0; k < HH; k += 4) {
        float4 h  = *(const float4*)&h2[b * HH + k];
        float4 w0 = *(const float4*)&w[k];
        float4 w1 = *(const float4*)&w[HH + k];
        z0 += h.x * w0.x + h.y * w0.y + h.z * w0.z + h.w * w0.w;
        z1 += h.x * w1.x + h.y * w1.y + h.z * w1.z + h.w * w1.w;
    }
    const float m  = fmaxf(z0, z1);
    const float e0 = expf(z0 - m), e1 = expf(z1 - m);
    const float inv = 1.f / (e0 + e1);
    out[b * 2 + 0] = e0 * inv;
    out[b * 2 + 1] = e1 * inv;
}

extern "C" void kernel_launch(void* const* d_in, const int* in_sizes, int n_in,
                              void* d_out, int out_size, void* d_ws, size_t ws_size,
                              hipStream_t stream)
{
    (void)in_sizes; (void)n_in; (void)out_size; (void)ws_size;
    const float* x    = (const float*)d_in[0];
    const float* Wih0 = (const float*)d_in[1];
    const float* Whh0 = (const float*)d_in[2];
    const float* bih0 = (const float*)d_in[3];
    const float* bhh0 = (const float*)d_in[4];
    const float* Wih1 = (const float*)d_in[5];
    const float* Whh1 = (const float*)d_in[6];
    const float* bih1 = (const float*)d_in[7];
    const float* bhh1 = (const float*)d_in[8];
    const float* fcw  = (const float*)d_in[9];
    const float* fcb  = (const float*)d_in[10];
    float* out = (float*)d_out;

    char* ws = (char*)d_ws;
    float* buf0 = (float*)(ws + BUF0_OFF);
    float* WT   = (float*)(ws + WT_OFF);
    float* h2l  = (float*)(ws + H2L_OFF);

    static bool attr_done = false;
    if (!attr_done) {
        hipFuncSetAttribute((const void*)scan_rnn<true>,
                            hipFuncAttributeMaxDynamicSharedMemorySize, SCAN_SMEM);
        hipFuncSetAttribute((const void*)scan_rnn<false>,
                            hipFuncAttributeMaxDynamicSharedMemorySize, SCAN_SMEM);
        attr_done = true;
    }

    // ---- layer 0 ----
    transpose_w<<<dim3(IN / 32, HH / 32), dim3(256), 0, stream>>>(Wih0, WT, IN);
    gemm_xw<IN><<<dim3(MM / 32), dim3(256), 32 * IN * 4, stream>>>(x, WT, bih0, bhh0, buf0);
    scan_rnn<true><<<dim3(BB), dim3(512), SCAN_SMEM, stream>>>(buf0, Whh0, buf0);

    // ---- layer 1 (WT buffer reused: lifetimes disjoint) ----
    transpose_w<<<dim3(HH / 32, HH / 32), dim3(256), 0, stream>>>(Wih1, WT, HH);
    gemm_xw<HH><<<dim3(MM / 32), dim3(256), 32 * HH * 4, stream>>>(buf0, WT, bih1, bhh1, buf0);
    scan_rnn<false><<<dim3(BB), dim3(512), SCAN_SMEM, stream>>>(buf0, Whh1, h2l);

    // ---- FC + softmax ----
    fc_kernel<<<dim3(1), dim3(64), 0, stream>>>(h2l, fcw, fcb, out);
}

// Round 3
// 8996.090 us; speedup vs baseline: 1.4451x; 1.4451x over previous
//
#include <hip/hip_runtime.h>
#include <hip/hip_fp16.h>

// RNN_14078902797083: 2-layer tanh RNN + FC + softmax, fp32 in/out.
// B=64, T=2048, IN=256, H=512, NCLASS=2.
//
// R7: the scan is LDS-instruction-throughput bound (R5/R6: ~640 LDS instr
// per step per CU ~= 3500-3900 cyc/step). Rebalance h distribution across
// pipes: each wave reads the FULL h vector with ONE lane-spread
// ds_read_b128 (lane c holds h-uints 4c..4c+3), then distributes h-uints
// 112..255 via v_readlane -> SGPR feeding v_dot2_f32_f16 scalar operand
// (VALU pipe, which has idle cycles), keeping only uints 0..111 as LDS
// broadcasts. Weights: KREG=384 in VGPRs (192 uints; allocator budget fixed
// via __launch_bounds__(512,2) -> 256 VGPRs; R6's waves_per_eu attr was
// ignored -> VGPR_Count stayed 128 and weights spilled), KLDS=128 in LDS.
// Projected ~1800 cyc/step balanced LDS/VALU.

#define BB 64
#define TT 2048
#define IN 256
#define HH 512
#define MM (BB * TT)          // 131072 rows

// workspace layout (bytes)
#define BUF0_OFF 0ull                      // [B][T][H] f32 = 256 MB (xw0 -> h1 -> xw1, in place)
#define WT_OFF   268435456ull              // W^T scratch, 1 MB (WT0 then WT1, disjoint lifetimes)
#define H2L_OFF  269484032ull              // [B][H] f32 last hidden = 128 KB

// ---- recurrent weight split ----
#define KREG 384                 // k-range held in VGPRs (48 uint4 = 192 regs)
#define KLDS (HH - KREG)         // 128 -> LDS as uint4 [KLDS/8][HH] = 128 KB
#define NCH_REG (KREG / 8)       // 48 uint4 weight chunks in VGPRs
#define NCH_LDS (KLDS / 8)       // 16 uint4 weight chunks in LDS
#define NB 28                    // h-uint4 chunks via LDS broadcast (uints 0..111)
#define SCAN_SMEM (NCH_LDS * HH * 16 + 2 * 256 * 4)   // 131072 + 2048 = 133120 B

typedef _Float16 v2h __attribute__((ext_vector_type(2)));

__device__ __forceinline__ float fdot2u(unsigned a, unsigned b, float c) {
#if __has_builtin(__builtin_amdgcn_fdot2)
    union { unsigned u; v2h h; } ua, ub;
    ua.u = a; ub.u = b;
    return __builtin_amdgcn_fdot2(ua.h, ub.h, c, false);
#else
    __half2 ah = *reinterpret_cast<__half2*>(&a);
    __half2 bh = *reinterpret_cast<__half2*>(&b);
    float2 fa = __half22float2(ah), fb = __half22float2(bh);
    return fmaf(fa.y, fb.y, fmaf(fa.x, fb.x, c));
#endif
}

__device__ __forceinline__ unsigned pk2(float x, float y) {
    unsigned lo = (unsigned)__half_as_ushort(__float2half(x));
    unsigned hi = (unsigned)__half_as_ushort(__float2half(y));
    return lo | (hi << 16);
}

__device__ __forceinline__ unsigned rdlane(unsigned v, int lane) {
    return (unsigned)__builtin_amdgcn_readlane((int)v, lane);
}

// fast tanh: copysign((1-e)/(1+e), x) with e = exp(-2|x|). No overflow for any x.
__device__ __forceinline__ float fast_tanh(float x) {
    const float ax = __builtin_fabsf(x);
    const float e  = __expf(-2.f * ax);
    const float r  = (1.f - e) * __builtin_amdgcn_rcpf(1.f + e);
    return __builtin_copysignf(r, x);
}

// -------------------- W transpose: W[512][K] -> WT[K][512] --------------------
__global__ void transpose_w(const float* __restrict__ W, float* __restrict__ WT, int K)
{
    __shared__ float tile[32][33];
    const int k0 = blockIdx.x * 32;
    const int c0 = blockIdx.y * 32;
    const int tx = threadIdx.x & 31;
    const int ty = threadIdx.x >> 5;          // 0..7
    #pragma unroll
    for (int i = ty; i < 32; i += 8)
        tile[i][tx] = W[(size_t)(c0 + i) * K + k0 + tx];   // coalesced along k
    __syncthreads();
    #pragma unroll
    for (int i = ty; i < 32; i += 8)
        WT[(size_t)(k0 + i) * HH + c0 + tx] = tile[tx][i]; // coalesced along c
}

// -------------------- input projection GEMM: out = A @ W^T + (b1+b2) ----------
// A [M][K] (may alias out), WT [K][512], out [M][512]. 32 rows/WG, full N.
// Full-K A staging in LDS BEFORE any write -> in-place safe per 32-row block.
template <int K>
__global__ __launch_bounds__(256, 2)
void gemm_xw(const float* A, const float* __restrict__ WT,
             const float* __restrict__ b1, const float* __restrict__ b2,
             float* out)
{
    extern __shared__ char smem[];
    float* As = (float*)smem;                 // [32][K]
    const int m0 = blockIdx.x * 32;
    const int tid = threadIdx.x;

    const float* Ab = A + (size_t)m0 * K;
    #pragma unroll
    for (int i = 0; i < (32 * K) / 1024; ++i) {
        const int idx = tid * 4 + i * 1024;
        *(float4*)&As[idx] = *(const float4*)&Ab[idx];
    }
    __syncthreads();

    const int tc = tid & 63;                  // col base lane; cols c = tc + 64*cc
    const int r0 = (tid >> 6) * 8;            // 8 rows per thread

    float acc[8][8];
    #pragma unroll
    for (int cc = 0; cc < 8; ++cc) {
        const int c = tc + 64 * cc;
        const float bb = b1[c] + b2[c];
        #pragma unroll
        for (int rr = 0; rr < 8; ++rr) acc[rr][cc] = bb;
    }

    #pragma unroll 2
    for (int k = 0; k < K; k += 4) {
        float4 av4[8];
        #pragma unroll
        for (int rr = 0; rr < 8; ++rr)
            av4[rr] = *(const float4*)&As[(r0 + rr) * K + k];   // wave-uniform: broadcast
        #pragma unroll
        for (int kk = 0; kk < 4; ++kk) {
            float wv[8];
            #pragma unroll
            for (int cc = 0; cc < 8; ++cc)
                wv[cc] = WT[(size_t)(k + kk) * HH + tc + 64 * cc];  // lane-consecutive: coalesced
            #pragma unroll
            for (int rr = 0; rr < 8; ++rr) {
                const float a = ((const float*)&av4[rr])[kk];
                #pragma unroll
                for (int cc = 0; cc < 8; ++cc)
                    acc[rr][cc] = fmaf(a, wv[cc], acc[rr][cc]);
            }
        }
    }

    #pragma unroll
    for (int rr = 0; rr < 8; ++rr) {
        float* orow = out + (size_t)(m0 + r0 + rr) * HH;
        #pragma unroll
        for (int cc = 0; cc < 8; ++cc)
            orow[tc + 64 * cc] = acc[rr][cc];
    }
}

// -------------------- recurrent scan: one WG per batch, no inter-WG comm ------
template <bool WRITE_SEQ>
__global__ __launch_bounds__(512, 2)
void scan_rnn(const float* xw,                 // [B][T][H]; aliased by hseq when WRITE_SEQ
              const float* __restrict__ Whh,   // [H][H]
              float* hseq)                     // WRITE_SEQ: [B][T][H] (alias of xw); else [B][H]
{
    extern __shared__ char smem[];
    uint4* wlds4   = (uint4*)smem;                              // [NCH_LDS][HH]
    unsigned* hpk  = (unsigned*)(smem + NCH_LDS * HH * 16);     // [2][256] packed fp16 h

    const int b = blockIdx.x;
    const int j = threadIdx.x;                 // output row 0..511
    const int l = j & 63;                      // lane

    // ---- one-time: W_hh row j, k=0..383 as 48 uint4 of packed fp16 ----
    const float* wrow = Whh + (size_t)j * HH;
    uint4 w4[NCH_REG];
    #pragma unroll
    for (int c = 0; c < NCH_REG; ++c) {
        const float* p = wrow + c * 8;
        const float4 f0 = *(const float4*)(p);
        const float4 f1 = *(const float4*)(p + 4);
        w4[c].x = pk2(f0.x, f0.y);
        w4[c].y = pk2(f0.z, f0.w);
        w4[c].z = pk2(f1.x, f1.y);
        w4[c].w = pk2(f1.z, f1.w);
    }
    // ---- k=384..511 -> LDS [NCH_LDS][HH] uint4, lane-consecutive ----
    #pragma unroll
    for (int qq = 0; qq < NCH_LDS; ++qq) {
        const float* p = wrow + KREG + qq * 8;
        const float4 f0 = *(const float4*)(p);
        const float4 f1 = *(const float4*)(p + 4);
        uint4 v;
        v.x = pk2(f0.x, f0.y); v.y = pk2(f0.z, f0.w);
        v.z = pk2(f1.x, f1.y); v.w = pk2(f1.z, f1.w);
        wlds4[qq * HH + j] = v;
    }
    __syncthreads();

    const float* xrow = xw + (size_t)b * TT * HH + j;
    float* srow = WRITE_SEQ ? (hseq + (size_t)b * TT * HH + j) : nullptr;

    float xw_cur = xrow[0];
    float xw_n1  = xrow[HH];
    for (int t = 0; t < TT; ++t) {
        const int t2 = (t + 2 < TT) ? (t + 2) : (TT - 1);
        const float xw_n2 = xrow[(size_t)t2 * HH];       // 2-deep prefetch

        float z = xw_cur;
        if (t > 0) {
            // read parity (t-1)&1
            const unsigned* hp = hpk + (((t & 1) ^ 1) * 256);
            // ONE lane-spread b128: lane c of this wave holds h-uints 4c..4c+3
            const uint4 hv = *(const uint4*)(hp + 4 * l);
            float a0 = 0.f, a1 = 0.f, a2 = 0.f, a3 = 0.f;
            // part 1: h-uints 0..111 via LDS uniform broadcast, weights w4[0..27]
            #pragma unroll
            for (int c = 0; c < NB; ++c) {
                const uint4 hb = *(const uint4*)(hp + 4 * c);
                a0 = fdot2u(w4[c].x, hb.x, a0);
                a1 = fdot2u(w4[c].y, hb.y, a1);
                a2 = fdot2u(w4[c].z, hb.z, a2);
                a3 = fdot2u(w4[c].w, hb.w, a3);
            }
            // part 2: h-uints 112..191 via readlane (SGPR dot2 operand), w4[28..47]
            #pragma unroll
            for (int c = NB; c < NCH_REG; ++c) {
                const unsigned s0 = rdlane(hv.x, c);
                const unsigned s1 = rdlane(hv.y, c);
                const unsigned s2 = rdlane(hv.z, c);
                const unsigned s3 = rdlane(hv.w, c);
                a0 = fdot2u(w4[c].x, s0, a0);
                a1 = fdot2u(w4[c].y, s1, a1);
                a2 = fdot2u(w4[c].z, s2, a2);
                a3 = fdot2u(w4[c].w, s3, a3);
            }
            // part 3: h-uints 192..255 via readlane, weights from LDS (lane-spread)
            #pragma unroll
            for (int qq = 0; qq < NCH_LDS; ++qq) {
                const uint4 wv = wlds4[qq * HH + j];
                const int c = NCH_REG + qq;        // lanes 48..63
                const unsigned s0 = rdlane(hv.x, c);
                const unsigned s1 = rdlane(hv.y, c);
                const unsigned s2 = rdlane(hv.z, c);
                const unsigned s3 = rdlane(hv.w, c);
                a0 = fdot2u(wv.x, s0, a0);
                a1 = fdot2u(wv.y, s1, a1);
                a2 = fdot2u(wv.z, s2, a2);
                a3 = fdot2u(wv.w, s3, a3);
            }
            z += (a0 + a1) + (a2 + a3);
        }
        const float h = fast_tanh(z);

        // publish h for next step (write parity t&1 != read parity -> 1 barrier/step)
        ((unsigned short*)(hpk + (t & 1) * 256))[j] = __half_as_ushort(__float2half(h));

        if (WRITE_SEQ) {
            srow[(size_t)t * HH] = h;          // in-place over xw[b][t][j]: thread-local element
        } else if (t == TT - 1) {
            hseq[b * HH + j] = h;
        }
        xw_cur = xw_n1;
        xw_n1  = xw_n2;
        __syncthreads();
    }
}

// -------------------- FC + softmax --------------------
__global__ void fc_kernel(const float* __restrict__ h2, const float* __restrict__ w,
                          const float* __restrict__ bvec, float* __restrict__ out)
{
    const int b = threadIdx.x;   // 64 threads
    float z0 = bvec[0], z1 = bvec[1];
    #pragma unroll 4
    for (int k = 0; k < HH; k += 4) {
        float4 h  = *(const float4*)&h2[b * HH + k];
        float4 w0 = *(const float4*)&w[k];
        float4 w1 = *(const float4*)&w[HH + k];
        z0 += h.x * w0.x + h.y * w0.y + h.z * w0.z + h.w * w0.w;
        z1 += h.x * w1.x + h.y * w1.y + h.z * w1.z + h.w * w1.w;
    }
    const float m  = fmaxf(z0, z1);
    const float e0 = expf(z0 - m), e1 = expf(z1 - m);
    const float inv = 1.f / (e0 + e1);
    out[b * 2 + 0] = e0 * inv;
    out[b * 2 + 1] = e1 * inv;
}

extern "C" void kernel_launch(void* const* d_in, const int* in_sizes, int n_in,
                              void* d_out, int out_size, void* d_ws, size_t ws_size,
                              hipStream_t stream)
{
    (void)in_sizes; (void)n_in; (void)out_size; (void)ws_size;
    const float* x    = (const float*)d_in[0];
    const float* Wih0 = (const float*)d_in[1];
    const float* Whh0 = (const float*)d_in[2];
    const float* bih0 = (const float*)d_in[3];
    const float* bhh0 = (const float*)d_in[4];
    const float* Wih1 = (const float*)d_in[5];
    const float* Whh1 = (const float*)d_in[6];
    const float* bih1 = (const float*)d_in[7];
    const float* bhh1 = (const float*)d_in[8];
    const float* fcw  = (const float*)d_in[9];
    const float* fcb  = (const float*)d_in[10];
    float* out = (float*)d_out;

    char* ws = (char*)d_ws;
    float* buf0 = (float*)(ws + BUF0_OFF);
    float* WT   = (float*)(ws + WT_OFF);
    float* h2l  = (float*)(ws + H2L_OFF);

    static bool attr_done = false;
    if (!attr_done) {
        hipFuncSetAttribute((const void*)scan_rnn<true>,
                            hipFuncAttributeMaxDynamicSharedMemorySize, SCAN_SMEM);
        hipFuncSetAttribute((const void*)scan_rnn<false>,
                            hipFuncAttributeMaxDynamicSharedMemorySize, SCAN_SMEM);
        attr_done = true;
    }

    // ---- layer 0 ----
    transpose_w<<<dim3(IN / 32, HH / 32), dim3(256), 0, stream>>>(Wih0, WT, IN);
    gemm_xw<IN><<<dim3(MM / 32), dim3(256), 32 * IN * 4, stream>>>(x, WT, bih0, bhh0, buf0);
    scan_rnn<true><<<dim3(BB), dim3(512), SCAN_SMEM, stream>>>(buf0, Whh0, buf0);

    // ---- layer 1 (WT buffer reused: lifetimes disjoint) ----
    transpose_w<<<dim3(HH / 32, HH / 32), dim3(256), 0, stream>>>(Wih1, WT, HH);
    gemm_xw<HH><<<dim3(MM / 32), dim3(256), 32 * HH * 4, stream>>>(buf0, WT, bih1, bhh1, buf0);
    scan_rnn<false><<<dim3(BB), dim3(512), SCAN_SMEM, stream>>>(buf0, Whh1, h2l);

    // ---- FC + softmax ----
    fc_kernel<<<dim3(1), dim3(64), 0, stream>>>(h2l, fcw, fcb, out);
}